// Round 3
// baseline (506.165 us; speedup 1.0000x reference)
//
#include <hip/hip_runtime.h>

#define Bn 16
#define Cn 128
#define Hn 128
#define Wn 128
#define Nn (Hn * Wn)   // 16384
#define KSPLIT 32      // split-K factor for the Gram kernel
#define LSTR 72        // LDS row stride in shorts for 64-wide k-chunks (144 B: 16B-aligned, same bank class as old 80 B)

typedef __attribute__((ext_vector_type(8))) short bf16x8;   // 8 bf16 = 4 VGPRs
typedef __attribute__((ext_vector_type(4))) float f32x4;

// round-to-nearest-even fp32 -> bf16 (bit pattern in ushort)
__device__ __forceinline__ unsigned short bfh(float f) {
    unsigned u = __float_as_uint(f);
    u += 0x7FFFu + ((u >> 16) & 1u);
    return (unsigned short)(u >> 16);
}
__device__ __forceinline__ float bf2f(unsigned short h) {
    return __uint_as_float(((unsigned)h) << 16);
}

// fragment read from a [128][LSTR] tile: row, k-substep s (0/1), quad
__device__ __forceinline__ bf16x8 ldfrag(const unsigned short* S, int row, int s, int quad) {
    return *(const bf16x8*)(S + row * LSTR + (s << 5) + (quad << 3));
}

// ---------------------------------------------------------------------------
// Kernel 1: G[b] = f . f^T via bf16-split MFMA (3-term), split-K(32).
// BK=64 (8 chunks, half the barriers); per-j B-fragment loads keep peak VGPR
// liveness ~110 so __launch_bounds__(256,2) holds WITHOUT scratch spills.
// Colsum fused during staging (deterministic per-wave partials).
// grid = 16 b * 32 ksplit = 512 blocks, 256 thr (4 waves, 2x2 of 64x64 tiles)
// ---------------------------------------------------------------------------
__global__ __launch_bounds__(256, 2) void gram_mfma(const float* __restrict__ x,
                                                    float* __restrict__ Gp,
                                                    float* __restrict__ colsum) {
    const int bid = blockIdx.x;
    const int ks = bid & 31;
    const int b = bid >> 5;
    const float* __restrict__ fb = x + (size_t)b * Cn * Nn;
    const int k0 = ks << 9;   // 512-wide K slice

    __shared__ __align__(16) unsigned short Shi[128 * LSTR];
    __shared__ __align__(16) unsigned short Slo[128 * LSTR];
    __shared__ float csumW[4][512];   // per-wave colsum partials (deterministic)

    const int tid = threadIdx.x;
    const int wave = tid >> 6, lane = tid & 63;
    const int m = lane & 15, quad = lane >> 4;
    const int wr = (wave >> 1) << 6;   // wave row base (0/64)
    const int wc = (wave & 1) << 6;    // wave col base (0/64)

    f32x4 acc[4][4];
#pragma unroll
    for (int i = 0; i < 4; ++i)
#pragma unroll
        for (int j = 0; j < 4; ++j) acc[i][j] = (f32x4){0.f, 0.f, 0.f, 0.f};

    for (int ck = 0; ck < 512; ck += 64) {
        __syncthreads();
        // stage 128c x 64k, fp32 -> (hi,lo) bf16; accumulate colsum partials
        float4 cs = {0.f, 0.f, 0.f, 0.f};
#pragma unroll
        for (int p = 0; p < 8; ++p) {
            const int q = tid + (p << 8);
            const int c = q >> 4;               // 0..127
            const int k4 = (q & 15) << 2;       // 0..60 (const across p: q&15 == tid&15)
            const float4 v = *(const float4*)(fb + (size_t)c * Nn + k0 + ck + k4);
            cs.x += v.x; cs.y += v.y; cs.z += v.z; cs.w += v.w;
            const float f0[4] = {v.x, v.y, v.z, v.w};
            unsigned short h[4], l[4];
#pragma unroll
            for (int e = 0; e < 4; ++e) {
                h[e] = bfh(f0[e]);
                l[e] = bfh(f0[e] - bf2f(h[e]));
            }
            *(ushort4*)(Shi + c * LSTR + k4) = make_ushort4(h[0], h[1], h[2], h[3]);
            *(ushort4*)(Slo + c * LSTR + k4) = make_ushort4(l[0], l[1], l[2], l[3]);
        }
        // reduce colsum over the 4 lanes (stride 16) sharing this k4 within the wave;
        // each wave covers a disjoint set of 32 c-rows per k-column.
        cs.x += __shfl_xor(cs.x, 16); cs.y += __shfl_xor(cs.y, 16);
        cs.z += __shfl_xor(cs.z, 16); cs.w += __shfl_xor(cs.w, 16);
        cs.x += __shfl_xor(cs.x, 32); cs.y += __shfl_xor(cs.y, 32);
        cs.z += __shfl_xor(cs.z, 32); cs.w += __shfl_xor(cs.w, 32);
        if (lane < 16) {
            float* dst = &csumW[wave][ck + (lane << 2)];
            dst[0] = cs.x; dst[1] = cs.y; dst[2] = cs.z; dst[3] = cs.w;
        }
        __syncthreads();

        // two 32-wide k-substeps; A resident (32 VGPR), B loaded per-j (8 VGPR)
#pragma unroll
        for (int s = 0; s < 2; ++s) {
            bf16x8 Ah[4], Al[4];
#pragma unroll
            for (int i = 0; i < 4; ++i) {
                Ah[i] = ldfrag(Shi, wr + (i << 4) + m, s, quad);
                Al[i] = ldfrag(Slo, wr + (i << 4) + m, s, quad);
            }
#pragma unroll
            for (int j = 0; j < 4; ++j) {
                const int br = wc + (j << 4) + m;
                const bf16x8 Bh = ldfrag(Shi, br, s, quad);
                const bf16x8 Bl = ldfrag(Slo, br, s, quad);
#pragma unroll
                for (int i = 0; i < 4; ++i) {
                    acc[i][j] = __builtin_amdgcn_mfma_f32_16x16x32_bf16(Ah[i], Bh, acc[i][j], 0, 0, 0);
                    acc[i][j] = __builtin_amdgcn_mfma_f32_16x16x32_bf16(Ah[i], Bl, acc[i][j], 0, 0, 0);
                    acc[i][j] = __builtin_amdgcn_mfma_f32_16x16x32_bf16(Al[i], Bh, acc[i][j], 0, 0, 0);
                }
            }
        }
    }

    // colsum for this block's disjoint 512-wide k-slice (deterministic wave order)
    for (int i = tid; i < 512; i += 256) {
        colsum[(size_t)b * Nn + k0 + i] =
            csumW[0][i] + csumW[1][i] + csumW[2][i] + csumW[3][i];
    }

    // deterministic partial store: Gp[ks][b][row][col]
    float* __restrict__ Gb = Gp + (((size_t)ks * Bn + b) << 14);
#pragma unroll
    for (int i = 0; i < 4; ++i)
#pragma unroll
        for (int j = 0; j < 4; ++j)
#pragma unroll
            for (int r = 0; r < 4; ++r) {
                const int row = wr + (i << 4) + (quad << 2) + r;
                const int col = wc + (j << 4) + m;
                Gb[(row << 7) + col] = acc[i][j][r];
            }
}

// ---------------------------------------------------------------------------
// Kernel 2 (prep): reduce the 32 split-K partials of row c of G[b], then
// rowmax (incl diag), Gdiag, and L = -(G with diag zeroed) as bf16 hi/lo.
// grid = 2048 rows, 128 thr
// ---------------------------------------------------------------------------
__global__ __launch_bounds__(128) void prep_kernel(const float* __restrict__ Gp,
                                                   unsigned short* __restrict__ Lhi,
                                                   unsigned short* __restrict__ Llo,
                                                   float* __restrict__ rowmax,
                                                   float* __restrict__ gdiag) {
    const int row = blockIdx.x;          // b*128 + c
    const int b = row >> 7;
    const int c = row & 127;
    const int t = threadIdx.x;

    // sum 32 partials (stride Bn*16384 floats = 1 MB; coalesced across t)
    const float* __restrict__ p = Gp + (((size_t)b) << 14) + (c << 7) + t;
    float v = 0.0f;
#pragma unroll
    for (int ks = 0; ks < KSPLIT; ++ks)
        v += p[(size_t)ks * ((size_t)Bn << 14)];

    __shared__ float red[128];
    red[t] = v;
    __syncthreads();
#pragma unroll
    for (int s = 64; s > 0; s >>= 1) {
        if (t < s) red[t] = fmaxf(red[t], red[t + s]);
        __syncthreads();
    }
    if (t == 0) rowmax[row] = red[0];
    if (t == c) gdiag[row] = v;
    const float l = (t == c) ? 0.0f : -v;
    const unsigned short h = bfh(l);
    Lhi[(size_t)row * Cn + t] = h;
    Llo[(size_t)row * Cn + t] = bfh(l - bf2f(h));
}

// ---------------------------------------------------------------------------
// Kernel 3: Y[b] = rowmax (x) colsum - Gdiag o f + L @ f   (L = -Goff, bf16 MFMA)
// BK=64 (2 chunks, 4 barriers total); A-fragments direct from global (L2-resident
// via XCD swizzle), B (f fp32->hi/lo transposed) LDS-staged; per-j B loads keep
// VGPR liveness under the launch_bounds(256,2) cap.
// grid = 2048 blocks, 256 thr
// ---------------------------------------------------------------------------
__global__ __launch_bounds__(256, 2) void ymm_mfma(const unsigned short* __restrict__ Lhi,
                                                   const unsigned short* __restrict__ Llo,
                                                   const float* __restrict__ x,
                                                   const float* __restrict__ colsum,
                                                   const float* __restrict__ rowmax,
                                                   const float* __restrict__ gdiag,
                                                   float* __restrict__ Y) {
    const int bid = blockIdx.x;
    const int xcd = bid & 7;
    const int j2 = bid >> 3;
    const int b = (xcd << 1) + (j2 & 1);   // XCD x owns batches 2x, 2x+1
    const int nt = j2 >> 1;                // 0..127
    const int n0 = nt << 7;

    const float* __restrict__ fb = x + (size_t)b * Cn * Nn;
    const unsigned short* __restrict__ Lhb = Lhi + (size_t)b * Cn * Cn;
    const unsigned short* __restrict__ Llb = Llo + (size_t)b * Cn * Cn;

    __shared__ __align__(16) unsigned short SBh[128 * LSTR];  // [n][d-chunk] (transposed f)
    __shared__ __align__(16) unsigned short SBl[128 * LSTR];

    const int tid = threadIdx.x;
    const int wave = tid >> 6, lane = tid & 63;
    const int m = lane & 15, quad = lane >> 4;
    const int wrc = (wave >> 1) << 6;   // c base
    const int wn = (wave & 1) << 6;     // n base

    f32x4 acc[4][4];
#pragma unroll
    for (int i = 0; i < 4; ++i)
#pragma unroll
        for (int j = 0; j < 4; ++j) acc[i][j] = (f32x4){0.f, 0.f, 0.f, 0.f};

#pragma unroll
    for (int dd = 0; dd < Cn; dd += 64) {
        __syncthreads();
        // stage B (f fp32 -> hi/lo), transposed: SB[n][d]; 128 n x 64 d
#pragma unroll
        for (int p = 0; p < 8; ++p) {
            const int q = tid + (p << 8);
            const int nl = q & 127;
            const int d4 = (q >> 7) << 2;   // 0..60
            unsigned short h[4], l[4];
#pragma unroll
            for (int e = 0; e < 4; ++e) {
                const float f0 = fb[(size_t)(dd + d4 + e) * Nn + n0 + nl];
                h[e] = bfh(f0);
                l[e] = bfh(f0 - bf2f(h[e]));
            }
            *(ushort4*)(SBh + nl * LSTR + d4) = make_ushort4(h[0], h[1], h[2], h[3]);
            *(ushort4*)(SBl + nl * LSTR + d4) = make_ushort4(l[0], l[1], l[2], l[3]);
        }
        __syncthreads();

        // two 32-wide d-substeps; A from global (L2), B per-j from LDS
#pragma unroll
        for (int s = 0; s < 2; ++s) {
            bf16x8 Ah[4], Al[4];
#pragma unroll
            for (int i = 0; i < 4; ++i) {
                const size_t ro = (size_t)(wrc + (i << 4) + m) * Cn + dd + (s << 5) + (quad << 3);
                Ah[i] = *(const bf16x8*)(Lhb + ro);
                Al[i] = *(const bf16x8*)(Llb + ro);
            }
#pragma unroll
            for (int j = 0; j < 4; ++j) {
                const int br = wn + (j << 4) + m;
                const bf16x8 Bh = ldfrag(SBh, br, s, quad);
                const bf16x8 Bl = ldfrag(SBl, br, s, quad);
#pragma unroll
                for (int i = 0; i < 4; ++i) {
                    acc[i][j] = __builtin_amdgcn_mfma_f32_16x16x32_bf16(Ah[i], Bh, acc[i][j], 0, 0, 0);
                    acc[i][j] = __builtin_amdgcn_mfma_f32_16x16x32_bf16(Ah[i], Bl, acc[i][j], 0, 0, 0);
                    acc[i][j] = __builtin_amdgcn_mfma_f32_16x16x32_bf16(Al[i], Bh, acc[i][j], 0, 0, 0);
                }
            }
        }
    }

    // epilogue: Y = rowmax*colsum - gdiag*f + acc
    float* __restrict__ Yb = Y + (size_t)b * Cn * Nn;
#pragma unroll
    for (int i = 0; i < 4; ++i)
#pragma unroll
        for (int r = 0; r < 4; ++r) {
            const int c = wrc + (i << 4) + (quad << 2) + r;
            const float rm = rowmax[(b << 7) + c];
            const float gd = gdiag[(b << 7) + c];
#pragma unroll
            for (int j = 0; j < 4; ++j) {
                const int n = n0 + wn + (j << 4) + m;
                const float cs = colsum[(size_t)b * Nn + n];
                const float fv = fb[(size_t)c * Nn + n];
                Yb[(size_t)c * Nn + n] = fmaf(rm, cs, fmaf(-gd, fv, acc[i][j][r]));
            }
        }
}

// ---------------------------------------------------------------------------
// Kernel 4 (fused): depthwise 3x3 conv + bias + softmax(dim=W) + epilogue
// (at its ~85 µs BW floor; LDS stride 131 is conflict-free — left as known-correct)
// ---------------------------------------------------------------------------
__global__ __launch_bounds__(256) void conv_softmax_kernel(const float* __restrict__ Yin,
                                                           const float* __restrict__ wgt,
                                                           const float* __restrict__ bias,
                                                           const float* __restrict__ x,
                                                           const float* __restrict__ gamma,
                                                           float* __restrict__ out,
                                                           float* __restrict__ atten) {
    const int pid = blockIdx.x;              // b*Cn + c
    const int c = pid & (Cn - 1);
    const size_t pbase = (size_t)pid * Nn;

    __shared__ __align__(16) float P[128][131];

    const int tid = threadIdx.x;

#pragma unroll
    for (int p = 0; p < 16; ++p) {
        const int q = tid + (p << 8);
        const int row = q >> 5;
        const int c4 = (q & 31) << 2;
        const float4 v = *(const float4*)(Yin + pbase + (size_t)row * Wn + c4);
        P[row][1 + c4 + 0] = v.x; P[row][1 + c4 + 1] = v.y;
        P[row][1 + c4 + 2] = v.z; P[row][1 + c4 + 3] = v.w;
    }
    if (tid < 128) { P[tid][0] = 0.0f; P[tid][129] = 0.0f; }

    float wk[9];
#pragma unroll
    for (int i = 0; i < 9; ++i) wk[i] = wgt[c * 9 + i];
    const float bs = bias[c];
    const float g = gamma[0];

    __syncthreads();

    const int h = tid >> 1;
    const int c0 = (tid & 1) << 6;

    float acc0[32], acc1[32];
#pragma unroll
    for (int w = 0; w < 32; ++w) { acc0[w] = bs; acc1[w] = bs; }

#pragma unroll
    for (int chunk = 0; chunk < 2; ++chunk) {
        float* acc = chunk ? acc1 : acc0;
        const int cb = c0 + (chunk << 5);
#pragma unroll
        for (int kh = 0; kh < 3; ++kh) {
            const int hh = h + kh - 1;
            if (hh < 0 || hh >= Hn) continue;
            float r[34];
#pragma unroll
            for (int i = 0; i < 34; ++i) r[i] = P[hh][cb + i];
            const float w0 = wk[kh * 3 + 0], w1 = wk[kh * 3 + 1], w2 = wk[kh * 3 + 2];
#pragma unroll
            for (int w = 0; w < 32; ++w)
                acc[w] = fmaf(w0, r[w], fmaf(w1, r[w + 1], fmaf(w2, r[w + 2], acc[w])));
        }
    }

    float m = -1e30f;
#pragma unroll
    for (int w = 0; w < 32; ++w) m = fmaxf(m, fmaxf(acc0[w], acc1[w]));
    m = fmaxf(m, __shfl_xor(m, 1));
    float s = 0.0f;
#pragma unroll
    for (int w = 0; w < 32; ++w) { acc0[w] = __expf(acc0[w] - m); s += acc0[w]; }
#pragma unroll
    for (int w = 0; w < 32; ++w) { acc1[w] = __expf(acc1[w] - m); s += acc1[w]; }
    s += __shfl_xor(s, 1);
    const float inv = 1.0f / s;

    __syncthreads();

#pragma unroll
    for (int w = 0; w < 32; ++w) {
        P[h][1 + c0 + w] = acc0[w] * inv;
        P[h][1 + c0 + 32 + w] = acc1[w] * inv;
    }
    __syncthreads();

#pragma unroll
    for (int p = 0; p < 16; ++p) {
        const int q = tid + (p << 8);
        const int row = q >> 5;
        const int c4 = (q & 31) << 2;
        float4 a;
        a.x = P[row][1 + c4 + 0]; a.y = P[row][1 + c4 + 1];
        a.z = P[row][1 + c4 + 2]; a.w = P[row][1 + c4 + 3];
        const float4 xv = *(const float4*)(x + pbase + (size_t)row * Wn + c4);
        float4 o;
        o.x = fmaf(g, a.x, xv.x); o.y = fmaf(g, a.y, xv.y);
        o.z = fmaf(g, a.z, xv.z); o.w = fmaf(g, a.w, xv.w);
        *(float4*)(atten + pbase + (size_t)row * Wn + c4) = a;
        *(float4*)(out + pbase + (size_t)row * Wn + c4) = o;
    }
}

// ---------------------------------------------------------------------------
extern "C" void kernel_launch(void* const* d_in, const int* in_sizes, int n_in,
                              void* d_out, int out_size, void* d_ws, size_t ws_size,
                              hipStream_t stream) {
    const float* x     = (const float*)d_in[0];
    const float* wgt   = (const float*)d_in[1];
    const float* bias  = (const float*)d_in[2];
    const float* gamma = (const float*)d_in[3];

    float* out   = (float*)d_out;
    float* atten = out + (size_t)Bn * Cn * Nn;

    // ws layout (34 MB): Gp[32 splits] | colsum | Lhi | Llo
    float* Gp = (float*)d_ws;                                       // 32 MB
    float* colsum = Gp + ((size_t)KSPLIT * Bn << 14);               // 1 MB
    unsigned short* Lhi = (unsigned short*)(colsum + (size_t)Bn * Nn);  // 0.5 MB
    unsigned short* Llo = Lhi + (size_t)Bn * Cn * Cn;               // 0.5 MB
    // small arrays live at the head of the atten region (free until K4)
    float* rowmax = atten;            // 2048 floats
    float* gdiag  = atten + 2048;     // 2048 floats

    float* Y = out;   // out-region reused as Y scratch; overwritten by K4

    gram_mfma<<<Bn * 32, 256, 0, stream>>>(x, Gp, colsum);
    prep_kernel<<<Bn * Cn, 128, 0, stream>>>(Gp, Lhi, Llo, rowmax, gdiag);
    ymm_mfma<<<Bn * 128, 256, 0, stream>>>(Lhi, Llo, x, colsum, rowmax, gdiag, Y);
    conv_softmax_kernel<<<Bn * Cn, 256, 0, stream>>>(Y, wgt, bias, x, gamma, out, atten);
}

// Round 4
// 497.660 us; speedup vs baseline: 1.0171x; 1.0171x over previous
//
#include <hip/hip_runtime.h>

#define Bn 16
#define Cn 128
#define Hn 128
#define Wn 128
#define Nn (Hn * Wn)   // 16384
#define KSPLIT 32      // split-K factor for the Gram kernel

typedef __attribute__((ext_vector_type(8))) short bf16x8;   // 8 bf16 = 4 VGPRs
typedef __attribute__((ext_vector_type(4))) float f32x4;

// round-to-nearest-even fp32 -> bf16 (bit pattern in ushort)
__device__ __forceinline__ unsigned short bfh(float f) {
    unsigned u = __float_as_uint(f);
    u += 0x7FFFu + ((u >> 16) & 1u);
    return (unsigned short)(u >> 16);
}
__device__ __forceinline__ float bf2f(unsigned short h) {
    return __uint_as_float(((unsigned)h) << 16);
}

__device__ __forceinline__ bf16x8 ldfrag(const unsigned short* S, int row, int quad) {
    return *(const bf16x8*)(S + row * 40 + quad * 8);
}

// ---------------------------------------------------------------------------
// Kernel 1: G[b] = f . f^T via bf16-split MFMA (3-term), split-K(32).
// R2 structure (best measured). Block decode b = bid&15 so all 32 ks-blocks of
// batch b land on XCD b%8 (bid mod 8 == b mod 8): each XCD's L2 holds its two
// batches' Gp partials (2 x 2 MiB) for prep to re-read as L2 hits.
// Colsum fused during staging (deterministic per-wave partials).
// grid = 512 blocks, 256 thr (4 waves, 2x2 of 64x64 tiles)
// ---------------------------------------------------------------------------
__global__ __launch_bounds__(256, 2) void gram_mfma(const float* __restrict__ x,
                                                    float* __restrict__ Gp,
                                                    float* __restrict__ colsum) {
    const int bid = blockIdx.x;
    const int b = bid & 15;    // XCD = bid%8 = b%8
    const int ks = bid >> 4;
    const float* __restrict__ fb = x + (size_t)b * Cn * Nn;
    const int k0 = ks << 9;   // 512-wide K slice

    __shared__ __align__(16) unsigned short Shi[128 * 40];
    __shared__ __align__(16) unsigned short Slo[128 * 40];
    __shared__ float csumW[4][512];   // per-wave colsum partials (deterministic)

    const int tid = threadIdx.x;
    const int wave = tid >> 6, lane = tid & 63;
    const int m = lane & 15, quad = lane >> 4;
    const int wr = (wave >> 1) << 6;   // wave row base (0/64)
    const int wc = (wave & 1) << 6;    // wave col base (0/64)

    f32x4 acc[4][4];
#pragma unroll
    for (int i = 0; i < 4; ++i)
#pragma unroll
        for (int j = 0; j < 4; ++j) acc[i][j] = (f32x4){0.f, 0.f, 0.f, 0.f};

    for (int ck = 0; ck < 512; ck += 32) {
        __syncthreads();
        // stage 128c x 32k, fp32 -> (hi,lo) bf16; accumulate colsum partials
        float4 cs = {0.f, 0.f, 0.f, 0.f};
#pragma unroll
        for (int p = 0; p < 4; ++p) {
            const int q = tid + (p << 8);
            const int c = q >> 3;
            const int k4 = (q & 7) << 2;
            const float4 v = *(const float4*)(fb + (size_t)c * Nn + k0 + ck + k4);
            cs.x += v.x; cs.y += v.y; cs.z += v.z; cs.w += v.w;
            const float f0[4] = {v.x, v.y, v.z, v.w};
            unsigned short h[4], l[4];
#pragma unroll
            for (int e = 0; e < 4; ++e) {
                h[e] = bfh(f0[e]);
                l[e] = bfh(f0[e] - bf2f(h[e]));
            }
            *(ushort4*)(Shi + c * 40 + k4) = make_ushort4(h[0], h[1], h[2], h[3]);
            *(ushort4*)(Slo + c * 40 + k4) = make_ushort4(l[0], l[1], l[2], l[3]);
        }
        // reduce colsum over the 8 lanes sharing this k4 (stride-8 xor tree);
        // each (wave,k) slot is written exactly once across the 16 chunks.
#pragma unroll
        for (int s = 8; s < 64; s <<= 1) {
            cs.x += __shfl_xor(cs.x, s);
            cs.y += __shfl_xor(cs.y, s);
            cs.z += __shfl_xor(cs.z, s);
            cs.w += __shfl_xor(cs.w, s);
        }
        if (lane < 8) {
            float* dst = &csumW[wave][ck + (lane << 2)];
            dst[0] = cs.x; dst[1] = cs.y; dst[2] = cs.z; dst[3] = cs.w;
        }
        __syncthreads();

        bf16x8 Ah[4], Al[4], Bh[4], Bl[4];
#pragma unroll
        for (int i = 0; i < 4; ++i) {
            Ah[i] = ldfrag(Shi, wr + (i << 4) + m, quad);
            Al[i] = ldfrag(Slo, wr + (i << 4) + m, quad);
            Bh[i] = ldfrag(Shi, wc + (i << 4) + m, quad);
            Bl[i] = ldfrag(Slo, wc + (i << 4) + m, quad);
        }
#pragma unroll
        for (int i = 0; i < 4; ++i)
#pragma unroll
            for (int j = 0; j < 4; ++j) {
                acc[i][j] = __builtin_amdgcn_mfma_f32_16x16x32_bf16(Ah[i], Bh[j], acc[i][j], 0, 0, 0);
                acc[i][j] = __builtin_amdgcn_mfma_f32_16x16x32_bf16(Ah[i], Bl[j], acc[i][j], 0, 0, 0);
                acc[i][j] = __builtin_amdgcn_mfma_f32_16x16x32_bf16(Al[i], Bh[j], acc[i][j], 0, 0, 0);
            }
    }

    // colsum for this block's disjoint 512-wide k-slice (deterministic wave order)
    for (int i = tid; i < 512; i += 256) {
        colsum[(size_t)b * Nn + k0 + i] =
            csumW[0][i] + csumW[1][i] + csumW[2][i] + csumW[3][i];
    }

    // deterministic partial store: Gp[ks][b][row][col]
    float* __restrict__ Gb = Gp + (((size_t)ks * Bn + b) << 14);
#pragma unroll
    for (int i = 0; i < 4; ++i)
#pragma unroll
        for (int j = 0; j < 4; ++j)
#pragma unroll
            for (int r = 0; r < 4; ++r) {
                const int row = wr + (i << 4) + (quad << 2) + r;
                const int col = wc + (j << 4) + m;
                Gb[(row << 7) + col] = acc[i][j][r];
            }
}

// ---------------------------------------------------------------------------
// Kernel 2 (prep): reduce the 32 split-K partials of row c of G[b], then
// rowmax (incl diag), Gdiag, and L = -(G with diag zeroed) as bf16 hi/lo.
// Block decode b = bid&15 so this block lands on XCD b%8 — the same XCD whose
// L2 holds batch b's Gp partials (written by gram) -> partial reads hit L2.
// grid = 2048 blocks, 128 thr
// ---------------------------------------------------------------------------
__global__ __launch_bounds__(128) void prep_kernel(const float* __restrict__ Gp,
                                                   unsigned short* __restrict__ Lhi,
                                                   unsigned short* __restrict__ Llo,
                                                   float* __restrict__ rowmax,
                                                   float* __restrict__ gdiag) {
    const int bid = blockIdx.x;
    const int b = bid & 15;    // XCD = bid%8 = b%8 (matches gram's placement)
    const int c = bid >> 4;
    const int row = (b << 7) + c;        // b*128 + c
    const int t = threadIdx.x;

    // sum 32 partials (stride Bn*16384 floats = 1 MB; coalesced across t)
    const float* __restrict__ p = Gp + (((size_t)b) << 14) + (c << 7) + t;
    float v = 0.0f;
#pragma unroll
    for (int ks = 0; ks < KSPLIT; ++ks)
        v += p[(size_t)ks * ((size_t)Bn << 14)];

    __shared__ float red[128];
    red[t] = v;
    __syncthreads();
#pragma unroll
    for (int s = 64; s > 0; s >>= 1) {
        if (t < s) red[t] = fmaxf(red[t], red[t + s]);
        __syncthreads();
    }
    if (t == 0) rowmax[row] = red[0];
    if (t == c) gdiag[row] = v;
    const float l = (t == c) ? 0.0f : -v;
    const unsigned short h = bfh(l);
    Lhi[(size_t)row * Cn + t] = h;
    Llo[(size_t)row * Cn + t] = bfh(l - bf2f(h));
}

// ---------------------------------------------------------------------------
// Kernel 3: Y[b] = rowmax (x) colsum - Gdiag o f + L @ f   (L = -Goff, bf16 MFMA)
// R2 structure (best measured): A-fragments direct from global (L is 64 KB/batch,
// L2-resident via XCD swizzle: 2 batches = 128 KB per XCD L2). Fragment =
// contiguous 16 B. Only B (f, fp32->hi/lo transposed) is LDS-staged.
// grid = 2048 blocks, 256 thr
// ---------------------------------------------------------------------------
__global__ __launch_bounds__(256, 2) void ymm_mfma(const unsigned short* __restrict__ Lhi,
                                                   const unsigned short* __restrict__ Llo,
                                                   const float* __restrict__ x,
                                                   const float* __restrict__ colsum,
                                                   const float* __restrict__ rowmax,
                                                   const float* __restrict__ gdiag,
                                                   float* __restrict__ Y) {
    const int bid = blockIdx.x;
    const int xcd = bid & 7;
    const int j2 = bid >> 3;
    const int b = (xcd << 1) + (j2 & 1);   // XCD x owns batches 2x, 2x+1
    const int nt = j2 >> 1;                // 0..127
    const int n0 = nt << 7;

    const float* __restrict__ fb = x + (size_t)b * Cn * Nn;
    const unsigned short* __restrict__ Lhb = Lhi + (size_t)b * Cn * Cn;
    const unsigned short* __restrict__ Llb = Llo + (size_t)b * Cn * Cn;

    __shared__ __align__(16) unsigned short SBh[128 * 40];  // [n][d-chunk] (transposed f)
    __shared__ __align__(16) unsigned short SBl[128 * 40];

    const int tid = threadIdx.x;
    const int wave = tid >> 6, lane = tid & 63;
    const int m = lane & 15, quad = lane >> 4;
    const int wrc = (wave >> 1) << 6;   // c base
    const int wn = (wave & 1) << 6;     // n base

    f32x4 acc[4][4];
#pragma unroll
    for (int i = 0; i < 4; ++i)
#pragma unroll
        for (int j = 0; j < 4; ++j) acc[i][j] = (f32x4){0.f, 0.f, 0.f, 0.f};

    for (int dd = 0; dd < Cn; dd += 32) {
        // A fragments straight from global (L2): issue early so latency hides
        // under B staging + barrier.
        bf16x8 Ah[4], Al[4];
#pragma unroll
        for (int i = 0; i < 4; ++i) {
            const size_t ro = (size_t)(wrc + (i << 4) + m) * Cn + dd + (quad << 3);
            Ah[i] = *(const bf16x8*)(Lhb + ro);
            Al[i] = *(const bf16x8*)(Llb + ro);
        }
        __syncthreads();
        // stage B (f fp32 -> hi/lo), transposed: SB[n][d]; thread owns 1 n, 4 d
#pragma unroll
        for (int p = 0; p < 4; ++p) {
            const int q = tid + (p << 8);
            const int nl = q & 127;
            const int d4 = (q >> 7) << 2;
            unsigned short h[4], l[4];
#pragma unroll
            for (int e = 0; e < 4; ++e) {
                const float f0 = fb[(size_t)(dd + d4 + e) * Nn + n0 + nl];
                h[e] = bfh(f0);
                l[e] = bfh(f0 - bf2f(h[e]));
            }
            *(ushort4*)(SBh + nl * 40 + d4) = make_ushort4(h[0], h[1], h[2], h[3]);
            *(ushort4*)(SBl + nl * 40 + d4) = make_ushort4(l[0], l[1], l[2], l[3]);
        }
        __syncthreads();

        bf16x8 Bh[4], Bl[4];
#pragma unroll
        for (int i = 0; i < 4; ++i) {
            Bh[i] = ldfrag(SBh, wn + (i << 4) + m, quad);
            Bl[i] = ldfrag(SBl, wn + (i << 4) + m, quad);
        }
#pragma unroll
        for (int i = 0; i < 4; ++i)
#pragma unroll
            for (int j = 0; j < 4; ++j) {
                acc[i][j] = __builtin_amdgcn_mfma_f32_16x16x32_bf16(Ah[i], Bh[j], acc[i][j], 0, 0, 0);
                acc[i][j] = __builtin_amdgcn_mfma_f32_16x16x32_bf16(Ah[i], Bl[j], acc[i][j], 0, 0, 0);
                acc[i][j] = __builtin_amdgcn_mfma_f32_16x16x32_bf16(Al[i], Bh[j], acc[i][j], 0, 0, 0);
            }
    }

    // epilogue: Y = rowmax*colsum - gdiag*f + acc  (fv reads hit L2: same 64 KB
    // x-tile the B-stage just streamed)
    float* __restrict__ Yb = Y + (size_t)b * Cn * Nn;
#pragma unroll
    for (int i = 0; i < 4; ++i)
#pragma unroll
        for (int r = 0; r < 4; ++r) {
            const int c = wrc + (i << 4) + (quad << 2) + r;
            const float rm = rowmax[(b << 7) + c];
            const float gd = gdiag[(b << 7) + c];
#pragma unroll
            for (int j = 0; j < 4; ++j) {
                const int n = n0 + wn + (j << 4) + m;
                const float cs = colsum[(size_t)b * Nn + n];
                const float fv = fb[(size_t)c * Nn + n];
                Yb[(size_t)c * Nn + n] = fmaf(rm, cs, fmaf(-gd, fv, acc[i][j][r]));
            }
        }
}

// ---------------------------------------------------------------------------
// Kernel 4 (fused): depthwise 3x3 conv + bias + softmax(dim=W) + epilogue
// (at its ~85 µs BW floor — left as known-correct)
// ---------------------------------------------------------------------------
__global__ __launch_bounds__(256) void conv_softmax_kernel(const float* __restrict__ Yin,
                                                           const float* __restrict__ wgt,
                                                           const float* __restrict__ bias,
                                                           const float* __restrict__ x,
                                                           const float* __restrict__ gamma,
                                                           float* __restrict__ out,
                                                           float* __restrict__ atten) {
    const int pid = blockIdx.x;              // b*Cn + c
    const int c = pid & (Cn - 1);
    const size_t pbase = (size_t)pid * Nn;

    __shared__ __align__(16) float P[128][131];

    const int tid = threadIdx.x;

#pragma unroll
    for (int p = 0; p < 16; ++p) {
        const int q = tid + (p << 8);
        const int row = q >> 5;
        const int c4 = (q & 31) << 2;
        const float4 v = *(const float4*)(Yin + pbase + (size_t)row * Wn + c4);
        P[row][1 + c4 + 0] = v.x; P[row][1 + c4 + 1] = v.y;
        P[row][1 + c4 + 2] = v.z; P[row][1 + c4 + 3] = v.w;
    }
    if (tid < 128) { P[tid][0] = 0.0f; P[tid][129] = 0.0f; }

    float wk[9];
#pragma unroll
    for (int i = 0; i < 9; ++i) wk[i] = wgt[c * 9 + i];
    const float bs = bias[c];
    const float g = gamma[0];

    __syncthreads();

    const int h = tid >> 1;
    const int c0 = (tid & 1) << 6;

    float acc0[32], acc1[32];
#pragma unroll
    for (int w = 0; w < 32; ++w) { acc0[w] = bs; acc1[w] = bs; }

#pragma unroll
    for (int chunk = 0; chunk < 2; ++chunk) {
        float* acc = chunk ? acc1 : acc0;
        const int cb = c0 + (chunk << 5);
#pragma unroll
        for (int kh = 0; kh < 3; ++kh) {
            const int hh = h + kh - 1;
            if (hh < 0 || hh >= Hn) continue;
            float r[34];
#pragma unroll
            for (int i = 0; i < 34; ++i) r[i] = P[hh][cb + i];
            const float w0 = wk[kh * 3 + 0], w1 = wk[kh * 3 + 1], w2 = wk[kh * 3 + 2];
#pragma unroll
            for (int w = 0; w < 32; ++w)
                acc[w] = fmaf(w0, r[w], fmaf(w1, r[w + 1], fmaf(w2, r[w + 2], acc[w])));
        }
    }

    float m = -1e30f;
#pragma unroll
    for (int w = 0; w < 32; ++w) m = fmaxf(m, fmaxf(acc0[w], acc1[w]));
    m = fmaxf(m, __shfl_xor(m, 1));
    float s = 0.0f;
#pragma unroll
    for (int w = 0; w < 32; ++w) { acc0[w] = __expf(acc0[w] - m); s += acc0[w]; }
#pragma unroll
    for (int w = 0; w < 32; ++w) { acc1[w] = __expf(acc1[w] - m); s += acc1[w]; }
    s += __shfl_xor(s, 1);
    const float inv = 1.0f / s;

    __syncthreads();

#pragma unroll
    for (int w = 0; w < 32; ++w) {
        P[h][1 + c0 + w] = acc0[w] * inv;
        P[h][1 + c0 + 32 + w] = acc1[w] * inv;
    }
    __syncthreads();

#pragma unroll
    for (int p = 0; p < 16; ++p) {
        const int q = tid + (p << 8);
        const int row = q >> 5;
        const int c4 = (q & 31) << 2;
        float4 a;
        a.x = P[row][1 + c4 + 0]; a.y = P[row][1 + c4 + 1];
        a.z = P[row][1 + c4 + 2]; a.w = P[row][1 + c4 + 3];
        const float4 xv = *(const float4*)(x + pbase + (size_t)row * Wn + c4);
        float4 o;
        o.x = fmaf(g, a.x, xv.x); o.y = fmaf(g, a.y, xv.y);
        o.z = fmaf(g, a.z, xv.z); o.w = fmaf(g, a.w, xv.w);
        *(float4*)(atten + pbase + (size_t)row * Wn + c4) = a;
        *(float4*)(out + pbase + (size_t)row * Wn + c4) = o;
    }
}

// ---------------------------------------------------------------------------
extern "C" void kernel_launch(void* const* d_in, const int* in_sizes, int n_in,
                              void* d_out, int out_size, void* d_ws, size_t ws_size,
                              hipStream_t stream) {
    const float* x     = (const float*)d_in[0];
    const float* wgt   = (const float*)d_in[1];
    const float* bias  = (const float*)d_in[2];
    const float* gamma = (const float*)d_in[3];

    float* out   = (float*)d_out;
    float* atten = out + (size_t)Bn * Cn * Nn;

    // ws layout (34 MB): Gp[32 splits] | colsum | Lhi | Llo
    float* Gp = (float*)d_ws;                                       // 32 MB
    float* colsum = Gp + ((size_t)KSPLIT * Bn << 14);               // 1 MB
    unsigned short* Lhi = (unsigned short*)(colsum + (size_t)Bn * Nn);  // 0.5 MB
    unsigned short* Llo = Lhi + (size_t)Bn * Cn * Cn;               // 0.5 MB
    // small arrays live at the head of the atten region (free until K4)
    float* rowmax = atten;            // 2048 floats
    float* gdiag  = atten + 2048;     // 2048 floats

    float* Y = out;   // out-region reused as Y scratch; overwritten by K4

    gram_mfma<<<Bn * 32, 256, 0, stream>>>(x, Gp, colsum);
    prep_kernel<<<Bn * Cn, 128, 0, stream>>>(Gp, Lhi, Llo, rowmax, gdiag);
    ymm_mfma<<<Bn * 128, 256, 0, stream>>>(Lhi, Llo, x, colsum, rowmax, gdiag, Y);
    conv_softmax_kernel<<<Bn * Cn, 256, 0, stream>>>(Y, wgt, bias, x, gamma, out, atten);
}